// Round 1
// baseline (1685.361 us; speedup 1.0000x reference)
//
#include <hip/hip_runtime.h>
#include <cstdint>
#include <cstddef>

#define BB 32
#define LL 2048
#define DD 64

// masked scores get a huge negative finite value: expf(s - m) == 0 exactly,
// identical post-softmax to the reference's -inf / -1e32 fills.
#define BIG_NEG (-3.0e38f)

// ---------------------------------------------------------------------------
// K1: raw masked scores  S[b][q][k] = (q·k)/8, masked -> BIG_NEG
// tile 128(q) x 128(k), 256 threads, 8x8 micro, D chunked by 32 in LDS
// ---------------------------------------------------------------------------
__global__ __launch_bounds__(256) void k_scores(
    const float* __restrict__ q, const float* __restrict__ kmat,
    const int* __restrict__ diag, const int* __restrict__ mask,
    float* __restrict__ attn)
{
    __shared__ __align__(16) float sQT[32][132];  // [d][row], pad 132
    __shared__ __align__(16) float sKT[32][132];  // [d][col]

    const int b  = blockIdx.z;
    const int q0 = blockIdx.y * 128;
    const int k0 = blockIdx.x * 128;
    const int t  = threadIdx.x;
    const int tx = t & 15;        // col group: cols 8*tx .. 8*tx+7
    const int ty = t >> 4;        // row group: rows 8*ty .. 8*ty+7

    const float* qb = q    + ((size_t)b * LL + q0) * DD;
    const float* kb = kmat + ((size_t)b * LL + k0) * DD;

    float acc[8][8];
    #pragma unroll
    for (int i = 0; i < 8; ++i)
        #pragma unroll
        for (int j = 0; j < 8; ++j) acc[i][j] = 0.0f;

    for (int dc = 0; dc < DD; dc += 32) {
        // stage 128 rows x 32 d of Q and K, transposed ([d][row])
        #pragma unroll
        for (int i = 0; i < 4; ++i) {
            int lin = t + 256 * i;        // 0..1023 float4 slots
            int row = lin >> 3;           // 0..127
            int dv  = lin & 7;            // d4 block 0..7
            float4 a = *(const float4*)(qb + (size_t)row * DD + dc + dv * 4);
            sQT[dv * 4 + 0][row] = a.x;
            sQT[dv * 4 + 1][row] = a.y;
            sQT[dv * 4 + 2][row] = a.z;
            sQT[dv * 4 + 3][row] = a.w;
            float4 c = *(const float4*)(kb + (size_t)row * DD + dc + dv * 4);
            sKT[dv * 4 + 0][row] = c.x;
            sKT[dv * 4 + 1][row] = c.y;
            sKT[dv * 4 + 2][row] = c.z;
            sKT[dv * 4 + 3][row] = c.w;
        }
        __syncthreads();

        #pragma unroll 8
        for (int d = 0; d < 32; ++d) {
            float4 a0 = *(const float4*)&sQT[d][ty * 8];
            float4 a1 = *(const float4*)&sQT[d][ty * 8 + 4];
            float4 b0 = *(const float4*)&sKT[d][tx * 8];
            float4 b1 = *(const float4*)&sKT[d][tx * 8 + 4];
            float aa[8] = {a0.x, a0.y, a0.z, a0.w, a1.x, a1.y, a1.z, a1.w};
            float bb[8] = {b0.x, b0.y, b0.z, b0.w, b1.x, b1.y, b1.z, b1.w};
            #pragma unroll
            for (int ri = 0; ri < 8; ++ri)
                #pragma unroll
                for (int ci = 0; ci < 8; ++ci)
                    acc[ri][ci] = fmaf(aa[ri], bb[ci], acc[ri][ci]);
        }
        __syncthreads();
    }

    // epilogue: scale by 1/8, apply masks, write raw scores
    #pragma unroll
    for (int ri = 0; ri < 8; ++ri) {
        int qq = q0 + ty * 8 + ri;
        size_t base = ((size_t)b * LL + qq) * LL + (size_t)(k0 + tx * 8);
        int4 dm0 = *(const int4*)(diag + base);
        int4 dm1 = *(const int4*)(diag + base + 4);
        int4 mk0 = *(const int4*)(mask + base);
        int4 mk1 = *(const int4*)(mask + base + 4);
        int dmv[8] = {dm0.x, dm0.y, dm0.z, dm0.w, dm1.x, dm1.y, dm1.z, dm1.w};
        int mkv[8] = {mk0.x, mk0.y, mk0.z, mk0.w, mk1.x, mk1.y, mk1.z, mk1.w};
        float o[8];
        #pragma unroll
        for (int ci = 0; ci < 8; ++ci) {
            float s = acc[ri][ci] * 0.125f;
            o[ci] = (dmv[ci] == 0 || mkv[ci] != 0) ? BIG_NEG : s;
        }
        *(float4*)(attn + base)     = make_float4(o[0], o[1], o[2], o[3]);
        *(float4*)(attn + base + 4) = make_float4(o[4], o[5], o[6], o[7]);
    }
}

// ---------------------------------------------------------------------------
// K2: in-place row softmax over L=2048. One block per (b,q) row.
// Row lives in registers: 256 threads x 8 floats.
// ---------------------------------------------------------------------------
__global__ __launch_bounds__(256) void k_softmax(float* __restrict__ attn)
{
    __shared__ float redm[4];
    __shared__ float reds[4];
    float* p = attn + (size_t)blockIdx.x * LL;
    const int t = threadIdx.x;
    const int wave = t >> 6, lane = t & 63;

    float4 x0 = ((const float4*)p)[t];         // elems 4t..4t+3
    float4 x1 = ((const float4*)p)[t + 256];   // elems 1024+4t..

    float m = fmaxf(fmaxf(fmaxf(x0.x, x0.y), fmaxf(x0.z, x0.w)),
                    fmaxf(fmaxf(x1.x, x1.y), fmaxf(x1.z, x1.w)));
    #pragma unroll
    for (int off = 32; off >= 1; off >>= 1)
        m = fmaxf(m, __shfl_xor(m, off, 64));
    if (lane == 0) redm[wave] = m;
    __syncthreads();
    m = fmaxf(fmaxf(redm[0], redm[1]), fmaxf(redm[2], redm[3]));

    x0.x = expf(x0.x - m); x0.y = expf(x0.y - m);
    x0.z = expf(x0.z - m); x0.w = expf(x0.w - m);
    x1.x = expf(x1.x - m); x1.y = expf(x1.y - m);
    x1.z = expf(x1.z - m); x1.w = expf(x1.w - m);

    float s = (x0.x + x0.y + x0.z + x0.w) + (x1.x + x1.y + x1.z + x1.w);
    #pragma unroll
    for (int off = 32; off >= 1; off >>= 1)
        s += __shfl_xor(s, off, 64);
    if (lane == 0) reds[wave] = s;
    __syncthreads();
    s = (reds[0] + reds[1]) + (reds[2] + reds[3]);

    float inv = 1.0f / s;
    x0.x *= inv; x0.y *= inv; x0.z *= inv; x0.w *= inv;
    x1.x *= inv; x1.y *= inv; x1.z *= inv; x1.w *= inv;
    ((float4*)p)[t]       = x0;
    ((float4*)p)[t + 256] = x1;
}

// ---------------------------------------------------------------------------
// K3: out[b][q][d] = sum_k P[b][q][k] * V[b][k][d]
// tile 128(q) x 64(d=full D), TK=64, 256 threads, 8x4 micro
// ---------------------------------------------------------------------------
__global__ __launch_bounds__(256) void k_pv(
    const float* __restrict__ attn, const float* __restrict__ v,
    float* __restrict__ out)
{
    __shared__ __align__(16) float sPT[64][132];  // [k][row]
    __shared__ __align__(16) float sV[64][68];    // [k][d]

    const int b  = blockIdx.y;
    const int q0 = blockIdx.x * 128;
    const int t  = threadIdx.x;
    const int tx = t & 15;        // cols 4*tx .. 4*tx+3
    const int ty = t >> 4;        // rows 8*ty .. 8*ty+7

    const float* pb = attn + ((size_t)b * LL + q0) * LL;
    const float* vb = v + (size_t)b * LL * DD;

    float acc[8][4];
    #pragma unroll
    for (int i = 0; i < 8; ++i)
        #pragma unroll
        for (int j = 0; j < 4; ++j) acc[i][j] = 0.0f;

    for (int k0 = 0; k0 < LL; k0 += 64) {
        // stage P tile 128 x 64, transposed
        #pragma unroll
        for (int i = 0; i < 8; ++i) {
            int lin = t + 256 * i;   // 0..2047 float4 slots
            int row = lin >> 4;      // 0..127
            int kv  = lin & 15;
            float4 a = *(const float4*)(pb + (size_t)row * LL + k0 + kv * 4);
            sPT[kv * 4 + 0][row] = a.x;
            sPT[kv * 4 + 1][row] = a.y;
            sPT[kv * 4 + 2][row] = a.z;
            sPT[kv * 4 + 3][row] = a.w;
        }
        // stage V tile 64 x 64, natural
        #pragma unroll
        for (int i = 0; i < 4; ++i) {
            int lin = t + 256 * i;   // 0..1023
            int row = lin >> 4;      // 0..63
            int dv  = lin & 15;
            *(float4*)&sV[row][dv * 4] =
                *(const float4*)(vb + (size_t)(k0 + row) * DD + dv * 4);
        }
        __syncthreads();

        #pragma unroll 8
        for (int kk = 0; kk < 64; ++kk) {
            float4 a0 = *(const float4*)&sPT[kk][ty * 8];
            float4 a1 = *(const float4*)&sPT[kk][ty * 8 + 4];
            float4 b0 = *(const float4*)&sV[kk][tx * 4];
            float aa[8] = {a0.x, a0.y, a0.z, a0.w, a1.x, a1.y, a1.z, a1.w};
            float bb[4] = {b0.x, b0.y, b0.z, b0.w};
            #pragma unroll
            for (int ri = 0; ri < 8; ++ri)
                #pragma unroll
                for (int ci = 0; ci < 4; ++ci)
                    acc[ri][ci] = fmaf(aa[ri], bb[ci], acc[ri][ci]);
        }
        __syncthreads();
    }

    #pragma unroll
    for (int ri = 0; ri < 8; ++ri) {
        float4 o = make_float4(acc[ri][0], acc[ri][1], acc[ri][2], acc[ri][3]);
        *(float4*)(out + ((size_t)b * LL + q0 + ty * 8 + ri) * DD + tx * 4) = o;
    }
}

// ---------------------------------------------------------------------------
extern "C" void kernel_launch(void* const* d_in, const int* in_sizes, int n_in,
                              void* d_out, int out_size, void* d_ws, size_t ws_size,
                              hipStream_t stream)
{
    const float* q    = (const float*)d_in[0];
    const float* k    = (const float*)d_in[1];
    const float* v    = (const float*)d_in[2];
    const int*   diag = (const int*)d_in[3];
    const int*   mask = (const int*)d_in[4];   // ASSUMPTION: bool uploaded as int32

    float* out  = (float*)d_out;                       // [B, L, D]
    float* attn = out + (size_t)BB * LL * DD;          // [B, L, L]

    k_scores <<<dim3(LL / 128, LL / 128, BB), 256, 0, stream>>>(q, k, diag, mask, attn);
    k_softmax<<<dim3(BB * LL),                256, 0, stream>>>(attn);
    k_pv     <<<dim3(LL / 128, BB),           256, 0, stream>>>(attn, v, out);
}